// Round 6
// baseline (453.529 us; speedup 1.0000x reference)
//
#include <hip/hip_runtime.h>
#include <math.h>

// Min-sum BP LDPC decoder, LDS-resident messages, degree-sorted checks.
// One block = one batch element; padded msg arena (~160 KB) lives in LDS.
//
// R7 = R5's bp_decode, BYTE-IDENTICAL (proven: 180.6 us, conflicts 1.62e7,
// zero spills, bit-exact pass) + PARALLEL SETUP.
//
//  - R6 post-mortem: bank-balancing perm changed the var-phase FP summation
//    order -> ~1e-6 marginal perturbations -> hard-decision flips near 0.5 ->
//    FAIL. Constraint: never reorder the reference's arithmetic. Reverted.
//  - R7 insight: bench_total - bp_decode ~= 187 us in EVERY round. That is
//    setup_sort: single-block (1 CU!) mask-scan + counting-sort + prefix,
//    launched inside every timed kernel_launch. It costs more than the
//    decoder. Replaced by 3 parallel dispatches (+ 512 B memset):
//      K1 setup_hist    (256 blocks): wave-per-check ballot -> global hist
//      K2 setup_prefix  (1 thread):   64-bin prefix; pack bin_start|pad_base
//                                     (stride depends only on degree, so
//                                     padded bases are closed-form per bin)
//      K3 setup_scatter (256 blocks): re-scan degree, per-bin atomic ordinal
//                                     o -> pos = bin_start+o,
//                                     pb = pad_base + o*stride(d)
//    Within-bin order becomes nondeterministic: harmless (equal-degree checks
//    are interchangeable; outputs route by original index; bit-exact).
//  - ws format consumed by bp_decode is UNCHANGED from R5.
//  - Guard (R4 lesson): fast path needs (2*MC+128) ints = 33280 B of d_ws and
//    max_dc <= 64; else fall back to the old single-block setup_sort.

#define BLOCK 1024
#define NV    8192          // N variables
#define MC    4096          // M checks
#define NE    32768         // E edges (N * DV, DV=4)
#define VPT   (NV / BLOCK)  // 8 vars per thread
#define CPT   (MC / BLOCK)  // 4 checks per thread
#define NITER 10
#define ALPHA 0.8f
#define CLAMP 20.0f
#define MSGW  40896         // padded arena words (159.9 KB)

// ws layout (ints):
//  [0 .. MC)          : pbase(16b) | deg<<16   (degree-sorted order)
//  [MC .. 2MC)        : original check index   (syndrome + check_adj lookup)
//  [2MC .. 2MC+64)    : hist -> packed (bin_start u16 | pad_base u16<<16)
//  [2MC+64 .. 2MC+128): per-bin running counters (zeroed by memset)

__device__ __forceinline__ int pad_stride(int d) { return d + 1 + (d & 1); }

// ---------------- fast setup: 3 parallel dispatches ----------------
__global__ __launch_bounds__(BLOCK)
void setup_hist(const float* __restrict__ check_mask, int max_dc,
                int* __restrict__ hist)
{
    const int c    = blockIdx.x * (BLOCK / 64) + (threadIdx.x >> 6);
    const int lane = threadIdx.x & 63;
    if (c >= MC) return;
    const float m = (lane < max_dc) ? check_mask[(size_t)c * max_dc + lane] : 0.0f;
    const unsigned long long bal = __ballot(m != 0.0f);
    if (lane == 0) atomicAdd(&hist[(int)__popcll(bal) & 63], 1);
}

__global__ void setup_prefix(int* __restrict__ ws)
{
    if (threadIdx.x == 0) {
        int* h = ws + 2 * MC;
        int cs = 0, ps = 0;                      // check-start, padded-start
        for (int d = 0; d < 64; ++d) {
            const int cnt = h[d];
            h[d] = (cs & 0xFFFF) | (ps << 16);   // ps <= ~39k fits u16
            cs += cnt;
            ps += cnt * pad_stride(d);
        }
    }
}

__global__ __launch_bounds__(BLOCK)
void setup_scatter(const float* __restrict__ check_mask, int max_dc,
                   int* __restrict__ ws)
{
    const int c    = blockIdx.x * (BLOCK / 64) + (threadIdx.x >> 6);
    const int lane = threadIdx.x & 63;
    if (c >= MC) return;
    const float m = (lane < max_dc) ? check_mask[(size_t)c * max_dc + lane] : 0.0f;
    const int d = (int)__popcll(__ballot(m != 0.0f));
    if (lane == 0) {
        const int o      = atomicAdd(ws + 2 * MC + 64 + d, 1);  // bin ordinal
        const int packed = ws[2 * MC + d];
        const int pos    = (packed & 0xFFFF) + o;
        const int pb     = (packed >> 16) + o * pad_stride(d);
        ws[pos]      = (pb & 0xFFFF) | (d << 16);
        ws[MC + pos] = c;
    }
}

// ---------------- fallback setup: single block (R5's, proven) ----------------
__global__ __launch_bounds__(BLOCK)
void setup_sort(const float* __restrict__ check_mask,
                const int*   __restrict__ check_adj,
                int max_dc, int* __restrict__ ws)
{
    __shared__ int hist[64], cbase[64], wsum[16];
    __shared__ int sdeg[MC];
    const int t = threadIdx.x;
    if (t < 64) hist[t] = 0;
    __syncthreads();
    int deg[CPT];
#pragma unroll
    for (int k = 0; k < CPT; ++k) {
        const int c = t + k * BLOCK;
        int d = 0;
        for (int j = 0; j < max_dc; ++j)
            d += (check_mask[(size_t)c * max_dc + j] != 0.0f) ? 1 : 0;
        deg[k] = d;
        atomicAdd(&hist[d & 63], 1);
    }
    __syncthreads();
    if (t == 0) {
        int s = 0;
        for (int i = 0; i < 64; ++i) { cbase[i] = s; s += hist[i]; }
    }
    __syncthreads();
#pragma unroll
    for (int k = 0; k < CPT; ++k) {
        const int pos = atomicAdd(&cbase[deg[k] & 63], 1);
        sdeg[pos]    = deg[k];
        ws[MC + pos] = t + k * BLOCK;
    }
    __syncthreads();
    int psz[CPT];
    int s = 0;
#pragma unroll
    for (int k = 0; k < CPT; ++k) {
        const int d = sdeg[4 * t + k];
        psz[k] = s;
        s += pad_stride(d);
    }
    const int lane = t & 63, wv = t >> 6;
    int run = s;
#pragma unroll
    for (int off = 1; off < 64; off <<= 1) {
        const int n = __shfl_up(run, off, 64);
        if (lane >= off) run += n;
    }
    if (lane == 63) wsum[wv] = run;
    __syncthreads();
    if (t == 0) {
        int acc = 0;
        for (int w = 0; w < 16; ++w) { const int v = wsum[w]; wsum[w] = acc; acc += v; }
    }
    __syncthreads();
    const int tb = wsum[wv] + (run - s);
#pragma unroll
    for (int k = 0; k < CPT; ++k) {
        const int i = 4 * t + k;
        ws[i] = ((tb + psz[k]) & 0xFFFF) | (sdeg[i] << 16);
    }
}

// ---------------- decoder (BYTE-IDENTICAL to R5's bp_decode) ----------------
template<int DMAX>
__device__ __forceinline__ void do_check(float* __restrict__ msg,
                                         int st, int d, float sgn, float pad)
{
    float x[DMAX];
    float min1 = pad, min2 = pad, prod = sgn;
#pragma unroll
    for (int j = 0; j < DMAX; ++j) {
        if (j >= d) break;
        x[j] = msg[st + j];
    }
#pragma unroll
    for (int j = 0; j < DMAX; ++j) {
        if (j >= d) break;
        prod = (x[j] < 0.0f) ? -prod : prod;            // sign(0)=+1 like ref
        const float a = fabsf(x[j]);
        min2 = __builtin_amdgcn_fmed3f(min1, min2, a);  // uses OLD min1
        min1 = fminf(min1, a);
    }
    const float vm1 = ALPHA * min1;
    const float vm2 = ALPHA * min2;
#pragma unroll
    for (int j = 0; j < DMAX; ++j) {
        if (j >= d) break;
        const float m = (fabsf(fabsf(x[j]) - min1) < 1e-9f) ? vm2 : vm1;  // ref tie rule
        const float v = m * prod;
        msg[st + j] = (x[j] < 0.0f) ? -v : v;           // excl_sign = prod * sign_j
    }
}

__device__ void do_check_big(float* __restrict__ msg,
                             int st, int d, float sgn, float pad)
{
    float min1 = pad, min2 = pad, prod = sgn;
    for (int j = 0; j < d; ++j) {
        const float xx = msg[st + j];
        prod = (xx < 0.0f) ? -prod : prod;
        const float a = fabsf(xx);
        min2 = __builtin_amdgcn_fmed3f(min1, min2, a);
        min1 = fminf(min1, a);
    }
    const float vm1 = ALPHA * min1;
    const float vm2 = ALPHA * min2;
    for (int j = 0; j < d; ++j) {
        const float xx = msg[st + j];
        const float m  = (fabsf(fabsf(xx) - min1) < 1e-9f) ? vm2 : vm1;
        const float v  = m * prod;
        msg[st + j] = (xx < 0.0f) ? -v : v;
    }
}

__global__ __launch_bounds__(BLOCK) __attribute__((amdgpu_waves_per_eu(4, 4)))
void bp_decode(const float* __restrict__ syndrome,    // (B, M)
               const float* __restrict__ llr_g,       // (B, N)
               const int*   __restrict__ var_adj,     // (N, 4)
               const int*   __restrict__ var_idx,     // (E,)
               const int*   __restrict__ check_adj,   // (M, max_dc)
               int max_dc,
               const int*   __restrict__ ws,          // sorted check info
               float* __restrict__ out,               // marginals | hard | converged
               int B)
{
    __shared__ float msg[MSGW];  // padded arena, in-place ctv/vtc
    __shared__ float sh_e0;      // |vtc[edge 0]| snapshot for reference's pad
    __shared__ int   mism;

    const int b = blockIdx.x;
    const int t = threadIdx.x;

    // ---- load sorted-check info; build pos[e] in LDS (aliasing msg) ----
    int cst[CPT], dsb[CPT];   // padded base; (deg<<1) | syndrome_bit
    {
        int* posL = (int*)msg;
#pragma unroll
        for (int k = 0; k < CPT; ++k) {
            const int i = t + k * BLOCK;
            const int w = ws[i];
            const int c = ws[MC + i];
            const int pb = w & 0xFFFF;
            const int d  = w >> 16;
            cst[k] = pb;
            const int sb = (syndrome[(size_t)b * MC + c] > 0.5f) ? 1 : 0;
            dsb[k] = (d << 1) | sb;
            const int st = check_adj[(size_t)c * max_dc];  // first edge (contiguous)
            for (int j = 0; j < d; ++j)
                posL[st + j] = pb + j;
        }
    }
    __syncthreads();

    // ---- edge-0 owner (for reference's pad = |vtc[0]| + 1e6) ----
    const int  v0  = var_idx[0];
    const int4 r0  = ((const int4*)var_adj)[v0];
    const int  j0  = (r0.y == 0) ? 1 : (r0.z == 0) ? 2 : (r0.w == 0) ? 3 : 0;
    const bool own = (t == (v0 & (BLOCK - 1)));
    const int  k0  = v0 >> 10;            // v0 / BLOCK

    // ---- var-side padded slots + LLRs into registers ----
    int   vs[VPT][4];
    float llr[VPT];
    {
        const int* posL = (const int*)msg;
#pragma unroll
        for (int k = 0; k < VPT; ++k) {
            const int v = t + k * BLOCK;
            const int4 a = ((const int4*)var_adj)[v];   // var degree is exactly 4
            vs[k][0] = posL[a.x]; vs[k][1] = posL[a.y];
            vs[k][2] = posL[a.z]; vs[k][3] = posL[a.w];
            llr[k] = llr_g[(size_t)b * NV + v];
        }
    }
    __syncthreads();

    for (int e = t; e < MSGW; e += BLOCK) msg[e] = 0.0f;   // ctv0 = 0
    __syncthreads();

    for (int it = 0; it < NITER; ++it) {
        // ---- variable phase: msg(ctv) -> msg(vtc), in place ----
#pragma unroll
        for (int k = 0; k < VPT; ++k) {
            const float c0 = msg[vs[k][0]];
            const float c1 = msg[vs[k][1]];
            const float c2 = msg[vs[k][2]];
            const float c3 = msg[vs[k][3]];
            const float tot  = ((c0 + c1) + c2) + c3;   // reference sum order
            const float bse  = llr[k] + tot;
            const float o0 = __builtin_amdgcn_fmed3f(bse - c0, -CLAMP, CLAMP);
            const float o1 = __builtin_amdgcn_fmed3f(bse - c1, -CLAMP, CLAMP);
            const float o2 = __builtin_amdgcn_fmed3f(bse - c2, -CLAMP, CLAMP);
            const float o3 = __builtin_amdgcn_fmed3f(bse - c3, -CLAMP, CLAMP);
            msg[vs[k][0]] = o0;
            msg[vs[k][1]] = o1;
            msg[vs[k][2]] = o2;
            msg[vs[k][3]] = o3;
            if (own && k == k0) {
                const float vv = (j0 == 0) ? o0 : (j0 == 1) ? o1
                               : (j0 == 2) ? o2 : o3;
                sh_e0 = fabsf(vv) + 1.0e6f;
            }
        }
        __syncthreads();
        const float pad = sh_e0;

        // ---- check phase: contiguous padded regions, in place ----
#pragma unroll
        for (int k = 0; k < CPT; ++k) {
            const int   d   = dsb[k] >> 1;
            const float sgn = (dsb[k] & 1) ? -1.0f : 1.0f;
            const int   st  = cst[k];
            if (d <= 8)       do_check<8>(msg, st, d, sgn, pad);
            else if (d <= 12) do_check<12>(msg, st, d, sgn, pad);
            else if (d <= 16) do_check<16>(msg, st, d, sgn, pad);
            else              do_check_big(msg, st, d, sgn, pad);
        }
        __syncthreads();
    }

    // ---- finale: marginals, hard decisions, convergence ----
    float marg[VPT], hard[VPT];
#pragma unroll
    for (int k = 0; k < VPT; ++k) {
        const float c0 = msg[vs[k][0]];
        const float c1 = msg[vs[k][1]];
        const float c2 = msg[vs[k][2]];
        const float c3 = msg[vs[k][3]];
        const float tot = ((c0 + c1) + c2) + c3;
        const float tl  = llr[k] + tot;
        const float mg  = 1.0f / (1.0f + expf(tl));   // sigmoid(-tl)
        marg[k] = mg;
        hard[k] = (mg > 0.5f) ? 1.0f : 0.0f;
    }
    if (t == 0) mism = 0;
    __syncthreads();   // all ctv reads done; safe to overwrite msg

    const size_t BN = (size_t)B * NV;
#pragma unroll
    for (int k = 0; k < VPT; ++k) {
        const int v = t + k * BLOCK;
        out[(size_t)b * NV + v]      = marg[k];        // output 0: marginals
        out[BN + (size_t)b * NV + v] = hard[k];        // output 1: hard_decision
        const float h = hard[k];                       // scatter hard bit to edges
        msg[vs[k][0]] = h;
        msg[vs[k][1]] = h;
        msg[vs[k][2]] = h;
        msg[vs[k][3]] = h;
    }
    __syncthreads();

    // syn_hat[c] = parity over the check's edges' hard bits; converged iff == syndrome
#pragma unroll
    for (int k = 0; k < CPT; ++k) {
        const int d  = dsb[k] >> 1;
        const int sb = dsb[k] & 1;
        const int st = cst[k];
        int par = 0;
        for (int j = 0; j < d; ++j)
            par ^= (msg[st + j] != 0.0f) ? 1 : 0;
        if (par != sb) mism = 1;   // benign race: all writers store 1
    }
    __syncthreads();
    if (t == 0) out[2 * BN + b] = mism ? 0.0f : 1.0f;  // output 2: converged
}

extern "C" void kernel_launch(void* const* d_in, const int* in_sizes, int n_in,
                              void* d_out, int out_size, void* d_ws, size_t ws_size,
                              hipStream_t stream) {
    const float* syndrome   = (const float*)d_in[0];
    const float* llr        = (const float*)d_in[1];
    const int*   var_adj    = (const int*)d_in[2];
    // d_in[3] var_adj_mask: all ones (DV=4 exact) — unused
    const int*   check_adj  = (const int*)d_in[4];
    const float* check_mask = (const float*)d_in[5];
    const int*   var_idx    = (const int*)d_in[6];
    // d_in[7] pcm_dense — unused
    float* out = (float*)d_out;
    int*   ws  = (int*)d_ws;

    const int B      = in_sizes[0] / MC;      // 256
    const int max_dc = in_sizes[4] / MC;

    const bool fast = (ws_size >= (size_t)((2 * MC + 128) * sizeof(int)))
                   && (max_dc <= 64);
    if (fast) {
        hipMemsetAsync(ws + 2 * MC, 0, 128 * sizeof(int), stream);
        setup_hist<<<MC / (BLOCK / 64), BLOCK, 0, stream>>>(check_mask, max_dc,
                                                            ws + 2 * MC);
        setup_prefix<<<1, 64, 0, stream>>>(ws);
        setup_scatter<<<MC / (BLOCK / 64), BLOCK, 0, stream>>>(check_mask, max_dc, ws);
    } else {
        setup_sort<<<1, BLOCK, 0, stream>>>(check_mask, check_adj, max_dc, ws);
    }
    bp_decode<<<B, BLOCK, 0, stream>>>(syndrome, llr, var_adj, var_idx,
                                       check_adj, max_dc, ws, out, B);
}